// Round 4
// baseline (777.275 us; speedup 1.0000x reference)
//
#include <hip/hip_runtime.h>

#define NS 1024   // spins / steps
#define NB 4096   // batch
#define NH 128    // hidden
#define RB 8      // batch rows per block (2 blocks/CU)
#define NT 512    // threads per block (8 waves)

typedef __attribute__((ext_vector_type(8))) short short8;
typedef __attribute__((ext_vector_type(4))) float f32x4;

__device__ __forceinline__ short f2bf(float x) {   // fp32 -> bf16 RNE
    unsigned u = __builtin_bit_cast(unsigned, x);
    u = (u + 0x7FFFu + ((u >> 16) & 1u)) >> 16;
    return (short)u;
}
__device__ __forceinline__ float vexp2(float x) {  // raw v_exp_f32 (2^x)
    float r;
    asm("v_exp_f32 %0, %1" : "=v"(r) : "v"(x));
    return r;
}

__global__ __launch_bounds__(NT, 4)
void pwf_kernel(const float* __restrict__ data_in,
                const float* __restrict__ W_ih,
                const float* __restrict__ W_hh,
                const float* __restrict__ b_ih,
                const float* __restrict__ b_hh,
                const float* __restrict__ W_lin,
                const float* __restrict__ b_lin,
                float* __restrict__ out)
{
    // bf16 h, 8 rows only, double-buffered. elem(row,col), row 0..7:
    //   offset = row*128 + (((col>>3) ^ row)*8) + (col&7)   [shorts]
    // XOR-swizzle spreads the 4 lane-groups' b128 reads over all 8 bank-quads.
    __shared__ __align__(16) short hlds[2][RB * NH];   // 4 KB
    __shared__ unsigned selm[2];        // input-select bits (8 used)
    __shared__ unsigned upm[4], dnm[4]; // output masks, ring (logits lag 1 step)

    const int tid = threadIdx.x;
    const int w   = tid >> 6;       // wave 0..7
    const int l   = tid & 63;       // lane
    const int g   = l >> 4;         // k-group 0..3
    const int n16 = l & 15;         // A-row / B-col within tile
    const int r8  = n16 & 7;        // real batch row (lanes 8..15 duplicate 0..7)
    const int b0  = blockIdx.x * RB;

    const float TL2E = 2.8853900817779268f;  // 2*log2(e)  (tanh exp pre-scale)
    const float L2E  = 1.4426950408889634f;  // log2(e)    (softmax pre-scale)

    // ---- B fragments: W_hh (pre-scaled) held in registers forever ----
    const int col = w * 16 + n16;            // 0..127
    short8 bfrag[4];
    #pragma unroll
    for (int kb = 0; kb < 4; ++kb) {
        const float* src = W_hh + col * NH + kb * 32 + g * 8;
        short8 v;
        #pragma unroll
        for (int i = 0; i < 8; ++i) v[i] = f2bf(TL2E * src[i]);
        bfrag[kb] = v;
    }
    // ---- logit B-fragments (wave 0): col0 = L2E*W_lin[0], col1 = L2E*W_lin[1] ----
    short8 lfrag[4];
    #pragma unroll
    for (int kb = 0; kb < 4; ++kb) {
        short8 v;
        #pragma unroll
        for (int i = 0; i < 8; ++i) {
            const int k = kb * 32 + g * 8 + i;
            const float x = (n16 == 0) ? W_lin[k]
                          : ((n16 == 1) ? W_lin[NH + k] : 0.0f);
            v[i] = f2bf(L2E * x);
        }
        lfrag[kb] = v;
    }

    const float cb  = b_ih[col] + b_hh[col];
    const float cv0 = TL2E * (W_ih[col * 2 + 0] + cb);
    const float cv1 = TL2E * (W_ih[col * 2 + 1] + cb);
    const float bl0 = L2E * b_lin[0];
    const float bl1 = L2E * b_lin[1];

    // A-read offsets (shorts); lanes n16>=8 duplicate row n16-8 (broadcast pairs)
    int aoff[4];
    #pragma unroll
    for (int kb = 0; kb < 4; ++kb)
        aoff[kb] = r8 * NH + (((kb * 4 + g) ^ r8) * 8);
    // h-write offsets per C-reg r (row = g*4+r; only g<2 rows are real)
    int woff[4];
    #pragma unroll
    for (int r = 0; r < 4; ++r) {
        const int row = g * 4 + r;
        woff[r] = row * NH + ((((col >> 3) ^ row) & 15) * 8) + (col & 7);
    }

    // ---- init ----
    ((uint2*)hlds)[tid] = make_uint2(0u, 0u);   // 512 thr * 8 B = both buffers
    if (tid == 0) { selm[0] = 0u; upm[0] = 0u; dnm[0] = 0u; }
    int cntup = 0, cntdn = 0;
    float su_next = 0.0f;
    if (w == 7) {
        const int rr = (l < RB) ? l : (RB - 1);
        su_next = data_in[(size_t)(b0 + rr) * 2];
    }
    __syncthreads();

    for (int t = 0; t < NS; ++t) {
        const int p = t & 1;
        const short* hr = hlds[p];
        short* hw = hlds[p ^ 1];

        const unsigned sel = selm[p];

        const short8 a0 = *(const short8*)&hr[aoff[0]];
        const short8 a1 = *(const short8*)&hr[aoff[1]];
        const short8 a2 = *(const short8*)&hr[aoff[2]];
        const short8 a3 = *(const short8*)&hr[aoff[3]];

        // ---- wave 0: logits for output t-1 from h_t fragments ----
        if (w == 0 && t > 0) {
            f32x4 z = {0.f, 0.f, 0.f, 0.f};
            f32x4 cl01 = __builtin_amdgcn_mfma_f32_16x16x32_bf16(a0, lfrag[0], z, 0, 0, 0);
            cl01 = __builtin_amdgcn_mfma_f32_16x16x32_bf16(a1, lfrag[1], cl01, 0, 0, 0);
            f32x4 cl23 = __builtin_amdgcn_mfma_f32_16x16x32_bf16(a2, lfrag[2], z, 0, 0, 0);
            cl23 = __builtin_amdgcn_mfma_f32_16x16x32_bf16(a3, lfrag[3], cl23, 0, 0, 0);
            float d[4], oth[4];
            #pragma unroll
            for (int r = 0; r < 4; ++r) d[r] = cl01[r] + cl23[r];
            #pragma unroll
            for (int r = 0; r < 4; ++r) oth[r] = __shfl_xor(d[r], 1);
            if (n16 == 0 && g < 2) {   // rows g*4+r in 0..7; lane n16=1 holds l1
                const unsigned um = upm[(t - 1) & 3];
                const unsigned dm = dnm[(t - 1) & 3];
                #pragma unroll
                for (int r = 0; r < 4; ++r) {
                    const int row = g * 4 + r;
                    const float e = vexp2((oth[r] + bl1) - (d[r] + bl0));
                    float p0 = __builtin_amdgcn_rcpf(1.0f + e);
                    float p1 = 1.0f - p0;
                    if ((um >> row) & 1u) { p0 = 0.0f; p1 = 1.0f; }
                    if ((dm >> row) & 1u) { p0 = 1.0f; p1 = 0.0f; }  // down overrides
                    *(float2*)&out[((size_t)(t - 1) * NB + b0 + row) * 2] =
                        make_float2(p0, p1);
                }
            }
        }

        // ---- recurrence: two independent accumulator pairs ----
        f32x4 z = {0.f, 0.f, 0.f, 0.f};
        f32x4 c01 = __builtin_amdgcn_mfma_f32_16x16x32_bf16(a0, bfrag[0], z, 0, 0, 0);
        c01 = __builtin_amdgcn_mfma_f32_16x16x32_bf16(a1, bfrag[1], c01, 0, 0, 0);
        f32x4 c23 = __builtin_amdgcn_mfma_f32_16x16x32_bf16(a2, bfrag[2], z, 0, 0, 0);
        c23 = __builtin_amdgcn_mfma_f32_16x16x32_bf16(a3, bfrag[3], c23, 0, 0, 0);

        const unsigned nib = (sel >> (g * 4)) & 0xFu;   // rows>=8 -> bits 0 (dup ok)
        float hn[4];
        #pragma unroll
        for (int r = 0; r < 4; ++r) {
            const float cv = (nib & (1u << r)) ? cv1 : cv0;
            const float e  = vexp2(c01[r] + c23[r] + cv);     // exp(2x) in log2 domain
            hn[r] = fmaf(__builtin_amdgcn_rcpf(e + 1.0f), -2.0f, 1.0f);  // tanh
        }
        if (g < 2) {   // only rows 0..7 are real; halves LDS write traffic
            unsigned pk01, pk23;
            asm("v_cvt_pk_bf16_f32 %0, %1, %2" : "=v"(pk01) : "v"(hn[0]), "v"(hn[1]));
            asm("v_cvt_pk_bf16_f32 %0, %1, %2" : "=v"(pk23) : "v"(hn[2]), "v"(hn[3]));
            hw[woff[0]] = (short)(pk01 & 0xFFFFu);
            hw[woff[1]] = (short)(pk01 >> 16);
            hw[woff[2]] = (short)(pk23 & 0xFFFFu);
            hw[woff[3]] = (short)(pk23 >> 16);
        }

        // ---- wave 7: spin consume + sel/masks + prefetch ----
        if (w == 7) {
            const int isup = (su_next > 0.5f) ? 1 : 0;   // channel0==1 -> spin==0
            cntup += isup;
            cntdn += 1 - isup;
            const unsigned long long bsel = __ballot(isup == 0);
            const unsigned long long bup  = __ballot(cntup >= NS / 2);
            const unsigned long long bdn  = __ballot(cntdn >= NS / 2);
            if (l == 0) {
                selm[p ^ 1]      = (unsigned)bsel & 0xFFu;   // for step t+1
                upm[(t + 1) & 3] = (unsigned)bup  & 0xFFu;   // for output t+1
                dnm[(t + 1) & 3] = (unsigned)bdn  & 0xFFu;
            }
            const int tn = (t + 1 < NS) ? (t + 1) : t;
            const int rr = (l < RB) ? l : (RB - 1);
            su_next = data_in[((size_t)tn * NB + b0 + rr) * 2];
        }
        __syncthreads();
    }

    // ---- epilogue: output NS-1 from h_NS (in hlds[0] after t=1023) ----
    if (w == 0) {
        const short* hr = hlds[0];
        const short8 a0 = *(const short8*)&hr[aoff[0]];
        const short8 a1 = *(const short8*)&hr[aoff[1]];
        const short8 a2 = *(const short8*)&hr[aoff[2]];
        const short8 a3 = *(const short8*)&hr[aoff[3]];
        f32x4 z = {0.f, 0.f, 0.f, 0.f};
        f32x4 cl01 = __builtin_amdgcn_mfma_f32_16x16x32_bf16(a0, lfrag[0], z, 0, 0, 0);
        cl01 = __builtin_amdgcn_mfma_f32_16x16x32_bf16(a1, lfrag[1], cl01, 0, 0, 0);
        f32x4 cl23 = __builtin_amdgcn_mfma_f32_16x16x32_bf16(a2, lfrag[2], z, 0, 0, 0);
        cl23 = __builtin_amdgcn_mfma_f32_16x16x32_bf16(a3, lfrag[3], cl23, 0, 0, 0);
        float d[4], oth[4];
        #pragma unroll
        for (int r = 0; r < 4; ++r) d[r] = cl01[r] + cl23[r];
        #pragma unroll
        for (int r = 0; r < 4; ++r) oth[r] = __shfl_xor(d[r], 1);
        if (n16 == 0 && g < 2) {
            const unsigned um = upm[(NS - 1) & 3];
            const unsigned dm = dnm[(NS - 1) & 3];
            #pragma unroll
            for (int r = 0; r < 4; ++r) {
                const int row = g * 4 + r;
                const float e = vexp2((oth[r] + bl1) - (d[r] + bl0));
                float p0 = __builtin_amdgcn_rcpf(1.0f + e);
                float p1 = 1.0f - p0;
                if ((um >> row) & 1u) { p0 = 0.0f; p1 = 1.0f; }
                if ((dm >> row) & 1u) { p0 = 1.0f; p1 = 0.0f; }
                *(float2*)&out[((size_t)(NS - 1) * NB + b0 + row) * 2] =
                    make_float2(p0, p1);
            }
        }
    }
}

extern "C" void kernel_launch(void* const* d_in, const int* in_sizes, int n_in,
                              void* d_out, int out_size, void* d_ws, size_t ws_size,
                              hipStream_t stream) {
    const float* data_in = (const float*)d_in[0];
    const float* W_ih    = (const float*)d_in[1];
    const float* W_hh    = (const float*)d_in[2];
    const float* b_ih    = (const float*)d_in[3];
    const float* b_hh    = (const float*)d_in[4];
    const float* W_lin   = (const float*)d_in[5];
    const float* b_lin   = (const float*)d_in[6];
    float* out = (float*)d_out;

    dim3 grid(NB / RB);   // 512 blocks -> 2 per CU (two independent chains)
    dim3 block(NT);       // 8 waves
    pwf_kernel<<<grid, block, 0, stream>>>(data_in, W_ih, W_hh, b_ih, b_hh,
                                           W_lin, b_lin, out);
}

// Round 5
// 662.900 us; speedup vs baseline: 1.1725x; 1.1725x over previous
//
#include <hip/hip_runtime.h>

#define NS 1024   // spins / steps
#define NB 4096   // batch
#define NH 128    // hidden
#define RB 16     // batch rows per block (= rows per CU)
#define NT 256    // threads per block (4 waves, 2 col-tiles each)

typedef __attribute__((ext_vector_type(8))) short short8;
typedef __attribute__((ext_vector_type(4))) float f32x4;

__device__ __forceinline__ short f2bf(float x) {   // fp32 -> bf16 RNE
    unsigned u = __builtin_bit_cast(unsigned, x);
    u = (u + 0x7FFFu + ((u >> 16) & 1u)) >> 16;
    return (short)u;
}
__device__ __forceinline__ float vexp2(float x) {  // raw v_exp_f32 (2^x)
    float r;
    asm("v_exp_f32 %0, %1" : "=v"(r) : "v"(x));
    return r;
}

__global__ __launch_bounds__(NT, 1)
void pwf_kernel(const float* __restrict__ data_in,
                const float* __restrict__ W_ih,
                const float* __restrict__ W_hh,
                const float* __restrict__ b_ih,
                const float* __restrict__ b_hh,
                const float* __restrict__ W_lin,
                const float* __restrict__ b_lin,
                float* __restrict__ out)
{
    // bf16 h, double-buffered. Rotated row-major layout (shorts):
    //   elem(row, col) at  row*128 + ((col + 8*row) & 127)
    // -> b128 A-frag reads: 16B-aligned, 8 lanes/bank-quad in distinct bank
    //    rows (8-clk floor, zero conflicts); b16 h-writes: 2-way max (free).
    __shared__ __align__(16) short hlds[2][RB * NH];   // 8 KB
    __shared__ unsigned selm[2];        // input-select bits (16 used)
    __shared__ unsigned upm[4], dnm[4]; // output-mask ring (logits lag 1 step)

    const int tid = threadIdx.x;
    const int w   = tid >> 6;       // wave 0..3
    const int l   = tid & 63;       // lane
    const int g   = l >> 4;         // k-group 0..3
    const int n16 = l & 15;         // A-row / B-col within tile
    const int b0  = blockIdx.x * RB;

    const float TL2E = 2.8853900817779268f;  // 2*log2(e)
    const float L2E  = 1.4426950408889634f;  // log2(e)

    // ---- B fragments: wave w owns col-tiles w and w+4 (W_hh in regs forever) ----
    const int colA = w * 16 + n16;           // tile A columns
    const int colB = colA + 64;              // tile B columns
    short8 bfA[4], bfB[4];
    #pragma unroll
    for (int kb = 0; kb < 4; ++kb) {
        const float* sa = W_hh + colA * NH + kb * 32 + g * 8;
        const float* sb = W_hh + colB * NH + kb * 32 + g * 8;
        short8 va, vb;
        #pragma unroll
        for (int i = 0; i < 8; ++i) { va[i] = f2bf(TL2E * sa[i]); vb[i] = f2bf(TL2E * sb[i]); }
        bfA[kb] = va; bfB[kb] = vb;
    }
    // ---- logit B-fragments (wave 0 only) ----
    short8 lfrag[4];
    #pragma unroll
    for (int kb = 0; kb < 4; ++kb) {
        short8 v;
        #pragma unroll
        for (int i = 0; i < 8; ++i) v[i] = 0;
        if (w == 0 && n16 < 2) {
            #pragma unroll
            for (int i = 0; i < 8; ++i)
                v[i] = f2bf(L2E * W_lin[n16 * NH + kb * 32 + g * 8 + i]);
        }
        lfrag[kb] = v;
    }

    const float cbA  = b_ih[colA] + b_hh[colA];
    const float cvA0 = TL2E * (W_ih[colA * 2 + 0] + cbA);
    const float cvA1 = TL2E * (W_ih[colA * 2 + 1] + cbA);
    const float cbB  = b_ih[colB] + b_hh[colB];
    const float cvB0 = TL2E * (W_ih[colB * 2 + 0] + cbB);
    const float cvB1 = TL2E * (W_ih[colB * 2 + 1] + cbB);
    const float bl0 = L2E * b_lin[0];
    const float bl1 = L2E * b_lin[1];

    // A-read offsets (shorts): row n16, cols kb*32+g*8.. ; rotation built in
    int aoff[4];
    #pragma unroll
    for (int kb = 0; kb < 4; ++kb)
        aoff[kb] = n16 * NH + ((kb * 32 + g * 8 + 8 * n16) & 127);
    // h-write offsets per C-reg r (row = 4g+r)
    int woffA[4], woffB[4];
    #pragma unroll
    for (int r = 0; r < 4; ++r) {
        const int row = 4 * g + r;
        woffA[r] = row * NH + ((colA + 8 * row) & 127);
        woffB[r] = row * NH + ((colB + 8 * row) & 127);
    }

    // ---- init ----
    ((uint4*)hlds)[tid]       = make_uint4(0u, 0u, 0u, 0u);   // h buffers = 0
    ((uint4*)hlds)[tid + NT]  = make_uint4(0u, 0u, 0u, 0u);
    if (tid == 0) { selm[0] = 0u; upm[0] = 0u; dnm[0] = 0u; }
    int cntup = 0, cntdn = 0;
    float su_next = 0.0f;
    if (w == 3) {
        const int rr = (l < RB) ? l : (RB - 1);
        su_next = data_in[(size_t)(b0 + rr) * 2];
    }
    __syncthreads();

    for (int t = 0; t < NS; ++t) {
        const int p = t & 1;
        const short* hr = hlds[p];
        short* hw = hlds[p ^ 1];

        const unsigned sel = selm[p];

        const short8 a0 = *(const short8*)&hr[aoff[0]];
        const short8 a1 = *(const short8*)&hr[aoff[1]];
        const short8 a2 = *(const short8*)&hr[aoff[2]];
        const short8 a3 = *(const short8*)&hr[aoff[3]];

        // ---- wave 0: logits for output t-1 from h_t fragments ----
        if (w == 0 && t > 0) {
            f32x4 cl = {0.f, 0.f, 0.f, 0.f};
            cl = __builtin_amdgcn_mfma_f32_16x16x32_bf16(a0, lfrag[0], cl, 0, 0, 0);
            cl = __builtin_amdgcn_mfma_f32_16x16x32_bf16(a1, lfrag[1], cl, 0, 0, 0);
            cl = __builtin_amdgcn_mfma_f32_16x16x32_bf16(a2, lfrag[2], cl, 0, 0, 0);
            cl = __builtin_amdgcn_mfma_f32_16x16x32_bf16(a3, lfrag[3], cl, 0, 0, 0);
            float oth[4];
            #pragma unroll
            for (int r = 0; r < 4; ++r) oth[r] = __shfl_xor(cl[r], 1);
            if (n16 == 0) {   // lanes 0,16,32,48 -> rows 4g+r, 16 rows total
                const unsigned um = upm[(t - 1) & 3];
                const unsigned dm = dnm[(t - 1) & 3];
                #pragma unroll
                for (int r = 0; r < 4; ++r) {
                    const int row = 4 * g + r;
                    const float e = vexp2((oth[r] + bl1) - (cl[r] + bl0));
                    float p0 = __builtin_amdgcn_rcpf(1.0f + e);
                    float p1 = 1.0f - p0;
                    if ((um >> row) & 1u) { p0 = 0.0f; p1 = 1.0f; }
                    if ((dm >> row) & 1u) { p0 = 1.0f; p1 = 0.0f; }  // down overrides
                    *(float2*)&out[((size_t)(t - 1) * NB + b0 + row) * 2] =
                        make_float2(p0, p1);
                }
            }
        }

        // ---- recurrence: two independent 4-deep MFMA chains ----
        f32x4 cA = {0.f, 0.f, 0.f, 0.f};
        f32x4 cB = {0.f, 0.f, 0.f, 0.f};
        cA = __builtin_amdgcn_mfma_f32_16x16x32_bf16(a0, bfA[0], cA, 0, 0, 0);
        cB = __builtin_amdgcn_mfma_f32_16x16x32_bf16(a0, bfB[0], cB, 0, 0, 0);
        cA = __builtin_amdgcn_mfma_f32_16x16x32_bf16(a1, bfA[1], cA, 0, 0, 0);
        cB = __builtin_amdgcn_mfma_f32_16x16x32_bf16(a1, bfB[1], cB, 0, 0, 0);
        cA = __builtin_amdgcn_mfma_f32_16x16x32_bf16(a2, bfA[2], cA, 0, 0, 0);
        cB = __builtin_amdgcn_mfma_f32_16x16x32_bf16(a2, bfB[2], cB, 0, 0, 0);
        cA = __builtin_amdgcn_mfma_f32_16x16x32_bf16(a3, bfA[3], cA, 0, 0, 0);
        cB = __builtin_amdgcn_mfma_f32_16x16x32_bf16(a3, bfB[3], cB, 0, 0, 0);

        float hA[4], hB[4];
        #pragma unroll
        for (int r = 0; r < 4; ++r) {
            const int bit = (sel >> (4 * g + r)) & 1;
            const float cva = bit ? cvA1 : cvA0;
            const float cvb = bit ? cvB1 : cvB0;
            const float eA = vexp2(cA[r] + cva);   // exp(2x) in log2 domain
            const float eB = vexp2(cB[r] + cvb);
            hA[r] = fmaf(__builtin_amdgcn_rcpf(eA + 1.0f), -2.0f, 1.0f);  // tanh
            hB[r] = fmaf(__builtin_amdgcn_rcpf(eB + 1.0f), -2.0f, 1.0f);
        }
        unsigned pA01, pA23, pB01, pB23;
        asm("v_cvt_pk_bf16_f32 %0, %1, %2" : "=v"(pA01) : "v"(hA[0]), "v"(hA[1]));
        asm("v_cvt_pk_bf16_f32 %0, %1, %2" : "=v"(pA23) : "v"(hA[2]), "v"(hA[3]));
        asm("v_cvt_pk_bf16_f32 %0, %1, %2" : "=v"(pB01) : "v"(hB[0]), "v"(hB[1]));
        asm("v_cvt_pk_bf16_f32 %0, %1, %2" : "=v"(pB23) : "v"(hB[2]), "v"(hB[3]));
        hw[woffA[0]] = (short)(pA01 & 0xFFFFu);
        hw[woffA[1]] = (short)(pA01 >> 16);
        hw[woffA[2]] = (short)(pA23 & 0xFFFFu);
        hw[woffA[3]] = (short)(pA23 >> 16);
        hw[woffB[0]] = (short)(pB01 & 0xFFFFu);
        hw[woffB[1]] = (short)(pB01 >> 16);
        hw[woffB[2]] = (short)(pB23 & 0xFFFFu);
        hw[woffB[3]] = (short)(pB23 >> 16);

        // ---- wave 3: spin consume + sel/masks + prefetch ----
        if (w == 3) {
            const int isup = (su_next > 0.5f) ? 1 : 0;   // channel0==1 -> spin==0
            cntup += isup;
            cntdn += 1 - isup;
            const unsigned long long bsel = __ballot(l < RB && isup == 0);
            const unsigned long long bup  = __ballot(l < RB && cntup >= NS / 2);
            const unsigned long long bdn  = __ballot(l < RB && cntdn >= NS / 2);
            if (l == 0) {
                selm[p ^ 1]      = (unsigned)bsel & 0xFFFFu;  // for step t+1
                upm[(t + 1) & 3] = (unsigned)bup  & 0xFFFFu;  // for output t+1
                dnm[(t + 1) & 3] = (unsigned)bdn  & 0xFFFFu;
            }
            const int tn = (t + 1 < NS) ? (t + 1) : t;
            const int rr = (l < RB) ? l : (RB - 1);
            su_next = data_in[((size_t)tn * NB + b0 + rr) * 2];
        }
        __syncthreads();
    }

    // ---- epilogue: output NS-1 from h_NS (in hlds[0] after t=1023) ----
    if (w == 0) {
        const short* hr = hlds[0];
        const short8 a0 = *(const short8*)&hr[aoff[0]];
        const short8 a1 = *(const short8*)&hr[aoff[1]];
        const short8 a2 = *(const short8*)&hr[aoff[2]];
        const short8 a3 = *(const short8*)&hr[aoff[3]];
        f32x4 cl = {0.f, 0.f, 0.f, 0.f};
        cl = __builtin_amdgcn_mfma_f32_16x16x32_bf16(a0, lfrag[0], cl, 0, 0, 0);
        cl = __builtin_amdgcn_mfma_f32_16x16x32_bf16(a1, lfrag[1], cl, 0, 0, 0);
        cl = __builtin_amdgcn_mfma_f32_16x16x32_bf16(a2, lfrag[2], cl, 0, 0, 0);
        cl = __builtin_amdgcn_mfma_f32_16x16x32_bf16(a3, lfrag[3], cl, 0, 0, 0);
        float oth[4];
        #pragma unroll
        for (int r = 0; r < 4; ++r) oth[r] = __shfl_xor(cl[r], 1);
        if (n16 == 0) {
            const unsigned um = upm[(NS - 1) & 3];
            const unsigned dm = dnm[(NS - 1) & 3];
            #pragma unroll
            for (int r = 0; r < 4; ++r) {
                const int row = 4 * g + r;
                const float e = vexp2((oth[r] + bl1) - (cl[r] + bl0));
                float p0 = __builtin_amdgcn_rcpf(1.0f + e);
                float p1 = 1.0f - p0;
                if ((um >> row) & 1u) { p0 = 0.0f; p1 = 1.0f; }
                if ((dm >> row) & 1u) { p0 = 1.0f; p1 = 0.0f; }
                *(float2*)&out[((size_t)(NS - 1) * NB + b0 + row) * 2] =
                    make_float2(p0, p1);
            }
        }
    }
}

extern "C" void kernel_launch(void* const* d_in, const int* in_sizes, int n_in,
                              void* d_out, int out_size, void* d_ws, size_t ws_size,
                              hipStream_t stream) {
    const float* data_in = (const float*)d_in[0];
    const float* W_ih    = (const float*)d_in[1];
    const float* W_hh    = (const float*)d_in[2];
    const float* b_ih    = (const float*)d_in[3];
    const float* b_hh    = (const float*)d_in[4];
    const float* W_lin   = (const float*)d_in[5];
    const float* b_lin   = (const float*)d_in[6];
    float* out = (float*)d_out;

    dim3 grid(NB / RB);   // 256 blocks, one 16-row chain per CU
    dim3 block(NT);       // 4 waves, 2 col-tiles each
    pwf_kernel<<<grid, block, 0, stream>>>(data_in, W_ih, W_hh, b_ih, b_hh,
                                           W_lin, b_lin, out);
}

// Round 6
// 425.851 us; speedup vs baseline: 1.8252x; 1.5566x over previous
//
#include <hip/hip_runtime.h>

#define NS 1024   // spins / steps
#define NB 4096   // batch
#define NH 128    // hidden
#define RB 16     // batch rows per block (= rows per CU)
#define NT 512    // threads per block (8 waves, 1 col-tile each)

typedef __attribute__((ext_vector_type(8))) short short8;
typedef __attribute__((ext_vector_type(4))) float f32x4;

__device__ __forceinline__ short f2bf(float x) {   // fp32 -> bf16 RNE
    unsigned u = __builtin_bit_cast(unsigned, x);
    u = (u + 0x7FFFu + ((u >> 16) & 1u)) >> 16;
    return (short)u;
}
__device__ __forceinline__ float vexp2(float x) {  // raw v_exp_f32 (2^x)
    float r;
    asm("v_exp_f32 %0, %1" : "=v"(r) : "v"(x));
    return r;
}

// LDS-only barrier: drain lgkm (h writes), do NOT drain vmcnt — the spin
// prefetch (wave 7) and out stores (wave 0) stay in flight across steps.
// __syncthreads would emit s_waitcnt vmcnt(0) here (m97 note) = ~900 cyc/step.
#define BARRIER() asm volatile("s_waitcnt lgkmcnt(0)\n\ts_barrier" ::: "memory")

// epilogue: softmax-from-logit-diff + mask + store out[tout] (ecl = log2e*(l1-l0))
__device__ __forceinline__ void epi_store(float e0, float e1, float e2, float e3,
                                          unsigned um, unsigned dm, int tout,
                                          int g, int n16, int b0,
                                          float* __restrict__ out)
{
    float ee[4] = {e0, e1, e2, e3};
    float P0[4], P1[4];
    #pragma unroll
    for (int r = 0; r < 4; ++r) {
        const float ex = vexp2(ee[r]);                     // exp(l1-l0)
        float p0 = __builtin_amdgcn_rcpf(1.0f + ex);       // softmax class 0
        float p1 = 1.0f - p0;
        const int row = 4 * g + r;
        if ((um >> row) & 1u) { p0 = 0.0f; p1 = 1.0f; }
        if ((dm >> row) & 1u) { p0 = 1.0f; p1 = 0.0f; }    // down overrides up
        P0[r] = p0; P1[r] = p1;
    }
    if (n16 == 0) {   // lanes 0,16,32,48: rows 4g..4g+3 -> 32 contiguous bytes
        float* dst = out + ((size_t)tout * NB + b0 + 4 * g) * 2;
        *(float4*)dst       = make_float4(P0[0], P1[0], P0[1], P1[1]);
        *(float4*)(dst + 4) = make_float4(P0[2], P1[2], P0[3], P1[3]);
    }
}

__global__ __launch_bounds__(NT, 1)
void pwf_kernel(const float* __restrict__ data_in,
                const float* __restrict__ W_ih,
                const float* __restrict__ W_hh,
                const float* __restrict__ b_ih,
                const float* __restrict__ b_hh,
                const float* __restrict__ W_lin,
                const float* __restrict__ b_lin,
                float* __restrict__ out)
{
    // bf16 h, double-buffered, rotated row-major (shorts):
    //   elem(row, col) at row*128 + ((col + 8*row) & 127)   (16B-aligned b128 reads)
    __shared__ __align__(16) short hlds[2][RB * NH];   // 8 KB
    __shared__ unsigned selm[2];   // input-select bits for step parity
    __shared__ uint2    msk[4];    // {up,dn} output-mask ring (epilogue lags 2)

    const int tid = threadIdx.x;
    const int w   = tid >> 6;       // wave 0..7
    const int l   = tid & 63;       // lane
    const int g   = l >> 4;         // k-group 0..3
    const int n16 = l & 15;         // A-row / B-col within tile
    const int b0  = blockIdx.x * RB;

    const float TL2E = 2.8853900817779268f;  // 2*log2(e)
    const float L2E  = 1.4426950408889634f;  // log2(e)

    // ---- B fragments: W_hh (exp2-domain) in registers forever ----
    const int col = w * 16 + n16;            // 0..127
    short8 bfrag[4];
    #pragma unroll
    for (int kb = 0; kb < 4; ++kb) {
        const float* src = W_hh + col * NH + kb * 32 + g * 8;
        short8 v;
        #pragma unroll
        for (int i = 0; i < 8; ++i) v[i] = f2bf(TL2E * src[i]);
        bfrag[kb] = v;
    }
    // ---- logit-diff B-fragments (wave 0): col 0 = log2e*(W_lin[1]-W_lin[0]) ----
    short8 lfrag[4];
    #pragma unroll
    for (int kb = 0; kb < 4; ++kb) {
        short8 v;
        #pragma unroll
        for (int i = 0; i < 8; ++i) {
            const int k = kb * 32 + g * 8 + i;
            v[i] = (n16 == 0) ? f2bf(L2E * (W_lin[NH + k] - W_lin[k])) : (short)0;
        }
        lfrag[kb] = v;
    }

    const float cb  = b_ih[col] + b_hh[col];
    const float cv0 = TL2E * (W_ih[col * 2 + 0] + cb);
    const float cv1 = TL2E * (W_ih[col * 2 + 1] + cb);
    const float blD = L2E * (b_lin[1] - b_lin[0]);

    int aoff[4];
    #pragma unroll
    for (int kb = 0; kb < 4; ++kb)
        aoff[kb] = n16 * NH + ((kb * 32 + g * 8 + 8 * n16) & 127);
    int woff[4];
    #pragma unroll
    for (int r = 0; r < 4; ++r) {
        const int row = 4 * g + r;
        woff[r] = row * NH + ((col + 8 * row) & 127);
    }

    // ---- init ----
    ((uint4*)hlds)[tid] = make_uint4(0u, 0u, 0u, 0u);   // 512*16B = both buffers
    if (tid == 0) { selm[0] = 0u; msk[0] = make_uint2(0u, 0u); }
    int cntup = 0, cntdn = 0;
    const int rr = (l < RB) ? l : (RB - 1);
    float suA = 0.0f, suB = 0.0f;        // spin ring, depth 2
    if (w == 7) {
        suA = data_in[(size_t)(b0 + rr) * 2];              // spin 0
        suB = data_in[((size_t)NB + b0 + rr) * 2];         // spin 1
    }
    float ecl0 = 0.f, ecl1 = 0.f, ecl2 = 0.f, ecl3 = 0.f; // wave0 saved logits
    unsigned eum = 0u, edm = 0u;                           // and masks
    BARRIER();

#define STEP(T, P, SU)                                                         \
    {                                                                          \
        const short* hr = hlds[P];                                             \
        short* hw = hlds[(P) ^ 1];                                             \
        const short8 a0 = *(const short8*)&hr[aoff[0]];                        \
        const short8 a1 = *(const short8*)&hr[aoff[1]];                        \
        const short8 a2 = *(const short8*)&hr[aoff[2]];                        \
        const short8 a3 = *(const short8*)&hr[aoff[3]];                        \
        const unsigned sel = selm[P];                                          \
        if (w == 0 && (T) >= 2)   /* deferred epilogue: store out[T-2] */      \
            epi_store(ecl0, ecl1, ecl2, ecl3, eum, edm, (T) - 2, g, n16, b0, out); \
        /* recurrence: two independent 2-deep MFMA chains */                   \
        f32x4 zz = {0.f, 0.f, 0.f, 0.f};                                       \
        f32x4 c01 = __builtin_amdgcn_mfma_f32_16x16x32_bf16(a0, bfrag[0], zz, 0, 0, 0); \
        c01 = __builtin_amdgcn_mfma_f32_16x16x32_bf16(a1, bfrag[1], c01, 0, 0, 0); \
        f32x4 c23 = __builtin_amdgcn_mfma_f32_16x16x32_bf16(a2, bfrag[2], zz, 0, 0, 0); \
        c23 = __builtin_amdgcn_mfma_f32_16x16x32_bf16(a3, bfrag[3], c23, 0, 0, 0); \
        if (w == 0 && (T) >= 1) { /* logits for out[T-1]; epilogue next step */ \
            f32x4 cl01 = __builtin_amdgcn_mfma_f32_16x16x32_bf16(a0, lfrag[0], zz, 0, 0, 0); \
            cl01 = __builtin_amdgcn_mfma_f32_16x16x32_bf16(a1, lfrag[1], cl01, 0, 0, 0); \
            f32x4 cl23 = __builtin_amdgcn_mfma_f32_16x16x32_bf16(a2, lfrag[2], zz, 0, 0, 0); \
            cl23 = __builtin_amdgcn_mfma_f32_16x16x32_bf16(a3, lfrag[3], cl23, 0, 0, 0); \
            ecl0 = cl01[0] + cl23[0] + blD;                                    \
            ecl1 = cl01[1] + cl23[1] + blD;                                    \
            ecl2 = cl01[2] + cl23[2] + blD;                                    \
            ecl3 = cl01[3] + cl23[3] + blD;                                    \
            const uint2 mm = msk[((T) - 1) & 3];                               \
            eum = mm.x; edm = mm.y;                                            \
        }                                                                      \
        const unsigned selg = sel >> (4 * g);                                  \
        float hn[4];                                                           \
        _Pragma("unroll")                                                      \
        for (int r = 0; r < 4; ++r) {                                          \
            const float cv = ((selg >> r) & 1u) ? cv1 : cv0;                   \
            const float e  = vexp2(c01[r] + c23[r] + cv);                      \
            hn[r] = fmaf(__builtin_amdgcn_rcpf(e + 1.0f), -2.0f, 1.0f);        \
        }                                                                      \
        unsigned pk01, pk23;                                                   \
        asm("v_cvt_pk_bf16_f32 %0, %1, %2" : "=v"(pk01) : "v"(hn[0]), "v"(hn[1])); \
        asm("v_cvt_pk_bf16_f32 %0, %1, %2" : "=v"(pk23) : "v"(hn[2]), "v"(hn[3])); \
        hw[woff[0]] = (short)(pk01 & 0xFFFFu);                                 \
        hw[woff[1]] = (short)(pk01 >> 16);                                     \
        hw[woff[2]] = (short)(pk23 & 0xFFFFu);                                 \
        hw[woff[3]] = (short)(pk23 >> 16);                                     \
        if (w == 7) {  /* spin consume + sel/masks + depth-2 prefetch */       \
            const int isup = ((SU) > 0.5f) ? 1 : 0;                            \
            cntup += isup; cntdn += 1 - isup;                                  \
            const unsigned long long bs = __ballot(isup == 0);                 \
            const unsigned long long bu = __ballot(cntup >= NS / 2);           \
            const unsigned long long bd = __ballot(cntdn >= NS / 2);           \
            if (l == 0) {                                                      \
                selm[(P) ^ 1] = (unsigned)bs & 0xFFFFu;                        \
                msk[((T) + 1) & 3] =                                           \
                    make_uint2((unsigned)bu & 0xFFFFu, (unsigned)bd & 0xFFFFu);\
            }                                                                  \
            const int tn = ((T) + 2 < NS) ? (T) + 2 : NS - 1;                  \
            (SU) = data_in[((size_t)tn * NB + b0 + rr) * 2];                   \
        }                                                                      \
        BARRIER();                                                             \
    }

    for (int t = 0; t < NS; t += 2) {
        STEP(t, 0, suA)
        STEP(t + 1, 1, suB)
    }

    // ---- post-loop: out[NS-2] (saved) and out[NS-1] (from h_NS in hlds[0]) ----
    if (w == 0) {
        epi_store(ecl0, ecl1, ecl2, ecl3, eum, edm, NS - 2, g, n16, b0, out);
        const short* hr = hlds[0];
        const short8 a0 = *(const short8*)&hr[aoff[0]];
        const short8 a1 = *(const short8*)&hr[aoff[1]];
        const short8 a2 = *(const short8*)&hr[aoff[2]];
        const short8 a3 = *(const short8*)&hr[aoff[3]];
        f32x4 zz = {0.f, 0.f, 0.f, 0.f};
        f32x4 cl01 = __builtin_amdgcn_mfma_f32_16x16x32_bf16(a0, lfrag[0], zz, 0, 0, 0);
        cl01 = __builtin_amdgcn_mfma_f32_16x16x32_bf16(a1, lfrag[1], cl01, 0, 0, 0);
        f32x4 cl23 = __builtin_amdgcn_mfma_f32_16x16x32_bf16(a2, lfrag[2], zz, 0, 0, 0);
        cl23 = __builtin_amdgcn_mfma_f32_16x16x32_bf16(a3, lfrag[3], cl23, 0, 0, 0);
        const uint2 mm = msk[(NS - 1) & 3];
        epi_store(cl01[0] + cl23[0] + blD, cl01[1] + cl23[1] + blD,
                  cl01[2] + cl23[2] + blD, cl01[3] + cl23[3] + blD,
                  mm.x, mm.y, NS - 1, g, n16, b0, out);
    }
}

extern "C" void kernel_launch(void* const* d_in, const int* in_sizes, int n_in,
                              void* d_out, int out_size, void* d_ws, size_t ws_size,
                              hipStream_t stream) {
    const float* data_in = (const float*)d_in[0];
    const float* W_ih    = (const float*)d_in[1];
    const float* W_hh    = (const float*)d_in[2];
    const float* b_ih    = (const float*)d_in[3];
    const float* b_hh    = (const float*)d_in[4];
    const float* W_lin   = (const float*)d_in[5];
    const float* b_lin   = (const float*)d_in[6];
    float* out = (float*)d_out;

    dim3 grid(NB / RB);   // 256 blocks, one 16-row chain per CU
    dim3 block(NT);       // 8 waves (2 per SIMD)
    pwf_kernel<<<grid, block, 0, stream>>>(data_in, W_ih, W_hh, b_ih, b_hh,
                                           W_lin, b_lin, out);
}

// Round 7
// 415.546 us; speedup vs baseline: 1.8705x; 1.0248x over previous
//
#include <hip/hip_runtime.h>

#define NS 1024   // spins / steps
#define NB 4096   // batch
#define NH 128    // hidden
#define RB 16     // batch rows per block (= rows per CU)
#define NT 512    // threads per block (8 waves)

typedef __attribute__((ext_vector_type(8))) short short8;
typedef __attribute__((ext_vector_type(4))) float f32x4;

__device__ __forceinline__ short f2bf(float x) {   // fp32 -> bf16 RNE
    unsigned u = __builtin_bit_cast(unsigned, x);
    u = (u + 0x7FFFu + ((u >> 16) & 1u)) >> 16;
    return (short)u;
}
__device__ __forceinline__ float vexp2(float x) {  // raw v_exp_f32 (2^x)
    float r;
    asm("v_exp_f32 %0, %1" : "=v"(r) : "v"(x));
    return r;
}

// LDS-only barrier: drain lgkm (h writes), NOT vmcnt — spin prefetch (wave 7)
// and out stores (wave 0) stay in flight across steps.
#define BARRIER() asm volatile("s_waitcnt lgkmcnt(0)\n\ts_barrier" ::: "memory")

__global__ __launch_bounds__(NT, 1)
void pwf_kernel(const float* __restrict__ data_in,
                const float* __restrict__ W_ih,
                const float* __restrict__ W_hh,
                const float* __restrict__ b_ih,
                const float* __restrict__ b_hh,
                const float* __restrict__ W_lin,
                const float* __restrict__ b_lin,
                float* __restrict__ out)
{
    // TRANSPOSED compute: D = W_hh · h^T  (A = W rows static; B = h, lane=batch;
    // C: lane=batch, regs=4 consecutive hidden) -> contiguous b64 h-writes.
    // LDS: bf16 h, elem(batch b, hid) at  b*128 + ((hid + 8*b) & 127)  [shorts]
    //  reads:  b128, 8 lanes per 4-bank span  = conflict-free optimum
    //  writes: b64,  4 lanes per 2-bank span  = conflict-free optimum
    __shared__ __align__(16) short hlds[2][RB * NH];   // 8 KB
    __shared__ unsigned selm[2];   // input-select bits (bit = batch row)
    __shared__ uint2    msk[4];    // {up,dn} mask ring (epilogue lags)

    const int tid = threadIdx.x;
    const int w   = tid >> 6;       // wave 0..7 (owns hidden rows 16w..16w+15)
    const int l   = tid & 63;       // lane
    const int g   = l >> 4;         // k-group 0..3
    const int b   = l & 15;         // batch column (N) / A-row (M)
    const int b0  = blockIdx.x * RB;

    const float TL2E = 2.8853900817779268f;  // 2*log2(e)
    const float L2E  = 1.4426950408889634f;  // log2(e)

    // ---- A fragments: W_hh rows (exp2-domain), registers forever ----
    const int hrow = w * 16 + b;             // hidden-out row this lane supplies
    short8 afrag[4];
    #pragma unroll
    for (int kb = 0; kb < 4; ++kb) {
        const float* src = W_hh + hrow * NH + kb * 32 + g * 8;
        short8 v;
        #pragma unroll
        for (int i = 0; i < 8; ++i) v[i] = f2bf(TL2E * src[i]);
        afrag[kb] = v;
    }
    // ---- logit A-fragment (wave 0): row 0 = log2e*(W_lin[1]-W_lin[0]) ----
    short8 lfrag[4];
    #pragma unroll
    for (int kb = 0; kb < 4; ++kb) {
        short8 v;
        #pragma unroll
        for (int i = 0; i < 8; ++i) {
            const int k = kb * 32 + g * 8 + i;
            v[i] = (b == 0) ? f2bf(L2E * (W_lin[NH + k] - W_lin[k])) : (short)0;
        }
        lfrag[kb] = v;
    }

    // ---- per-C-reg input contributions: hid = w*16 + 4g + r ----
    float cv0[4], cv1[4];
    #pragma unroll
    for (int r = 0; r < 4; ++r) {
        const int hid = w * 16 + 4 * g + r;
        const float cb = b_ih[hid] + b_hh[hid];
        cv0[r] = TL2E * (W_ih[hid * 2 + 0] + cb);
        cv1[r] = TL2E * (W_ih[hid * 2 + 1] + cb);
    }
    const float blD = L2E * (b_lin[1] - b_lin[0]);

    // ---- LDS offsets (shorts) ----
    int aoff[4];   // B-frag reads: elem(b, kb*32+g*8 .. +7)
    #pragma unroll
    for (int kb = 0; kb < 4; ++kb)
        aoff[kb] = b * NH + ((kb * 32 + g * 8 + 8 * b) & 127);
    const int woffs = b * NH + ((w * 16 + 4 * g + 8 * b) & 127);  // 1 b64 write

    // ---- init ----
    ((uint4*)hlds)[tid] = make_uint4(0u, 0u, 0u, 0u);   // 512*16B = both buffers
    if (tid == 0) { selm[0] = 0u; msk[0] = make_uint2(0u, 0u); }
    int cntup = 0, cntdn = 0;
    const int rr = (l < RB) ? l : (RB - 1);
    float suA = 0.0f, suB = 0.0f;        // spin ring, depth 2
    if (w == 7) {
        suA = data_in[(size_t)(b0 + rr) * 2];              // spin 0
        suB = data_in[((size_t)NB + b0 + rr) * 2];         // spin 1
    }
    float ediff = 0.0f;                  // wave0 saved logit-diff (out[T-2])
    unsigned eum = 0u, edm = 0u;
    BARRIER();

#define STEP(T, P, SU)                                                         \
    {                                                                          \
        const short* hr = hlds[P];                                             \
        short* hw = hlds[(P) ^ 1];                                             \
        const unsigned sel = selm[P];                                          \
        const short8 h0 = *(const short8*)&hr[aoff[0]];                        \
        const short8 h1 = *(const short8*)&hr[aoff[1]];                        \
        const short8 h2 = *(const short8*)&hr[aoff[2]];                        \
        const short8 h3 = *(const short8*)&hr[aoff[3]];                        \
        if (w == 0 && (T) >= 2 && l < 16) {  /* deferred store out[T-2] */     \
            float p0 = __builtin_amdgcn_rcpf(1.0f + vexp2(ediff));             \
            float p1 = 1.0f - p0;                                              \
            if ((eum >> l) & 1u) { p0 = 0.0f; p1 = 1.0f; }                     \
            if ((edm >> l) & 1u) { p0 = 1.0f; p1 = 0.0f; }                     \
            *(float2*)&out[((size_t)((T) - 2) * NB + b0 + l) * 2] =            \
                make_float2(p0, p1);                                           \
        }                                                                      \
        /* recurrence: two independent 2-deep MFMA chains */                   \
        f32x4 zz = {0.f, 0.f, 0.f, 0.f};                                       \
        f32x4 c01 = __builtin_amdgcn_mfma_f32_16x16x32_bf16(afrag[0], h0, zz, 0, 0, 0); \
        c01 = __builtin_amdgcn_mfma_f32_16x16x32_bf16(afrag[1], h1, c01, 0, 0, 0); \
        f32x4 c23 = __builtin_amdgcn_mfma_f32_16x16x32_bf16(afrag[2], h2, zz, 0, 0, 0); \
        c23 = __builtin_amdgcn_mfma_f32_16x16x32_bf16(afrag[3], h3, c23, 0, 0, 0); \
        if (w == 0 && (T) >= 1) {  /* logit-diffs for out[T-1] */              \
            f32x4 d01 = __builtin_amdgcn_mfma_f32_16x16x32_bf16(lfrag[0], h0, zz, 0, 0, 0); \
            d01 = __builtin_amdgcn_mfma_f32_16x16x32_bf16(lfrag[1], h1, d01, 0, 0, 0); \
            f32x4 d23 = __builtin_amdgcn_mfma_f32_16x16x32_bf16(lfrag[2], h2, zz, 0, 0, 0); \
            d23 = __builtin_amdgcn_mfma_f32_16x16x32_bf16(lfrag[3], h3, d23, 0, 0, 0); \
            ediff = d01[0] + d23[0] + blD;   /* valid on lanes 0..15 (g=0) */  \
            const uint2 mm = msk[((T) - 1) & 3];                               \
            eum = mm.x; edm = mm.y;                                            \
        }                                                                      \
        const unsigned sb = (sel >> b) & 1u;                                   \
        float hn[4];                                                           \
        _Pragma("unroll")                                                      \
        for (int r = 0; r < 4; ++r) {                                          \
            const float cv = sb ? cv1[r] : cv0[r];                             \
            const float e  = vexp2(c01[r] + c23[r] + cv);                      \
            hn[r] = fmaf(__builtin_amdgcn_rcpf(e + 1.0f), -2.0f, 1.0f);        \
        }                                                                      \
        unsigned pk01, pk23;                                                   \
        asm("v_cvt_pk_bf16_f32 %0, %1, %2" : "=v"(pk01) : "v"(hn[0]), "v"(hn[1])); \
        asm("v_cvt_pk_bf16_f32 %0, %1, %2" : "=v"(pk23) : "v"(hn[2]), "v"(hn[3])); \
        *(uint2*)&hw[woffs] = make_uint2(pk01, pk23);   /* one ds_write_b64 */ \
        if (w == 7) {  /* spin consume + sel/masks + depth-2 prefetch */       \
            const int isup = ((SU) > 0.5f) ? 1 : 0;                            \
            cntup += isup; cntdn += 1 - isup;                                  \
            const unsigned long long bs = __ballot(l < RB && isup == 0);       \
            const unsigned long long bu = __ballot(l < RB && cntup >= NS / 2); \
            const unsigned long long bd = __ballot(l < RB && cntdn >= NS / 2); \
            if (l == 0) {                                                      \
                selm[(P) ^ 1] = (unsigned)bs & 0xFFFFu;                        \
                msk[((T) + 1) & 3] =                                           \
                    make_uint2((unsigned)bu & 0xFFFFu, (unsigned)bd & 0xFFFFu);\
            }                                                                  \
            const int tn = ((T) + 2 < NS) ? (T) + 2 : NS - 1;                  \
            (SU) = data_in[((size_t)tn * NB + b0 + rr) * 2];                   \
        }                                                                      \
        BARRIER();                                                             \
    }

    for (int t = 0; t < NS; t += 2) {
        STEP(t, 0, suA)
        STEP(t + 1, 1, suB)
    }

    // ---- post-loop: flush out[NS-2]; out[NS-1] from h_NS (in hlds[0]) ----
    if (w == 0) {
        if (l < 16) {
            float p0 = __builtin_amdgcn_rcpf(1.0f + vexp2(ediff));
            float p1 = 1.0f - p0;
            if ((eum >> l) & 1u) { p0 = 0.0f; p1 = 1.0f; }
            if ((edm >> l) & 1u) { p0 = 1.0f; p1 = 0.0f; }
            *(float2*)&out[((size_t)(NS - 2) * NB + b0 + l) * 2] =
                make_float2(p0, p1);
        }
        const short* hr = hlds[0];
        const short8 h0 = *(const short8*)&hr[aoff[0]];
        const short8 h1 = *(const short8*)&hr[aoff[1]];
        const short8 h2 = *(const short8*)&hr[aoff[2]];
        const short8 h3 = *(const short8*)&hr[aoff[3]];
        f32x4 zz = {0.f, 0.f, 0.f, 0.f};
        f32x4 d01 = __builtin_amdgcn_mfma_f32_16x16x32_bf16(lfrag[0], h0, zz, 0, 0, 0);
        d01 = __builtin_amdgcn_mfma_f32_16x16x32_bf16(lfrag[1], h1, d01, 0, 0, 0);
        f32x4 d23 = __builtin_amdgcn_mfma_f32_16x16x32_bf16(lfrag[2], h2, zz, 0, 0, 0);
        d23 = __builtin_amdgcn_mfma_f32_16x16x32_bf16(lfrag[3], h3, d23, 0, 0, 0);
        const float fdiff = d01[0] + d23[0] + blD;
        const uint2 mm = msk[(NS - 1) & 3];
        if (l < 16) {
            float p0 = __builtin_amdgcn_rcpf(1.0f + vexp2(fdiff));
            float p1 = 1.0f - p0;
            if ((mm.x >> l) & 1u) { p0 = 0.0f; p1 = 1.0f; }
            if ((mm.y >> l) & 1u) { p0 = 1.0f; p1 = 0.0f; }
            *(float2*)&out[((size_t)(NS - 1) * NB + b0 + l) * 2] =
                make_float2(p0, p1);
        }
    }
}

extern "C" void kernel_launch(void* const* d_in, const int* in_sizes, int n_in,
                              void* d_out, int out_size, void* d_ws, size_t ws_size,
                              hipStream_t stream) {
    const float* data_in = (const float*)d_in[0];
    const float* W_ih    = (const float*)d_in[1];
    const float* W_hh    = (const float*)d_in[2];
    const float* b_ih    = (const float*)d_in[3];
    const float* b_hh    = (const float*)d_in[4];
    const float* W_lin   = (const float*)d_in[5];
    const float* b_lin   = (const float*)d_in[6];
    float* out = (float*)d_out;

    dim3 grid(NB / RB);   // 256 blocks, one 16-row chain per CU
    dim3 block(NT);       // 8 waves (2 per SIMD)
    pwf_kernel<<<grid, block, 0, stream>>>(data_in, W_ih, W_hh, b_ih, b_hh,
                                           W_lin, b_lin, out);
}